// Round 4
// baseline (321.558 us; speedup 1.0000x reference)
//
#include <hip/hip_runtime.h>
#include <math.h>

#define BB 4
#define HH 96
#define WW 96
#define CC 256
#define FF 256
#define HW (HH*WW)          // 9216
#define PTOT (BB*HW)        // 36864
#define NTAP 9

// workspace layout (float units):
//   w_frag: [16][72][64][8] bf16 (main conv B-frags)   294912
//   wof   : [2][72][64][8] bf16 (offset conv B-frags)   36864
//   xb16  : [PTOT][256] bf16                           4718592
#define WF_OFF  0
#define WOF_OFF (WF_OFF + 16*72*64*8/2)
#define XB_OFF  (WOF_OFF + 2*72*64*8/2)

typedef __attribute__((ext_vector_type(8))) short short8;   // 8 bf16
typedef __attribute__((ext_vector_type(4))) float floatx4;  // MFMA acc

struct alignas(16) F4 { float x, y, z, w; };
__device__ __forceinline__ F4 ldf4(const float* p) { return *(const F4*)p; }

__device__ __forceinline__ unsigned int pk2_bf16(float a, float b) {
    unsigned int ua = __float_as_uint(a); ua += 0x7FFFu + ((ua >> 16) & 1u);
    unsigned int ub = __float_as_uint(b); ub += 0x7FFFu + ((ub >> 16) & 1u);
    return (ua >> 16) | (ub & 0xFFFF0000u);
}
__device__ __forceinline__ float blo(unsigned int u) { return __uint_as_float(u << 16); }
__device__ __forceinline__ float bhi(unsigned int u) { return __uint_as_float(u & 0xFFFF0000u); }
__device__ __forceinline__ short8 zero8() { short8 v = {0,0,0,0,0,0,0,0}; return v; }

// ---------------------------------------------------------------------------
// x fp32 -> bf16 (8 elems/thread)
__global__ __launch_bounds__(256) void k_cast(const float* __restrict__ x,
                                              unsigned short* __restrict__ xb) {
    const int id = blockIdx.x * 256 + threadIdx.x;
    const F4 a = ldf4(x + (size_t)id * 8);
    const F4 b = ldf4(x + (size_t)id * 8 + 4);
    uint4 v;
    v.x = pk2_bf16(a.x, a.y); v.y = pk2_bf16(a.z, a.w);
    v.z = pk2_bf16(b.x, b.y); v.w = pk2_bf16(b.z, b.w);
    *(uint4*)(xb + (size_t)id * 8) = v;
}

// ---------------------------------------------------------------------------
// w_conv [2304 k][256 f] fp32 -> bf16 B-fragments:
// w_frag[ft][kc][lane][j] = w_conv[kc*32+(lane>>4)*8+j][ft*16+(lane&15)]
__global__ __launch_bounds__(256) void k_wfrag(const float* __restrict__ w_conv,
                                               unsigned short* __restrict__ w_frag) {
    const int id = blockIdx.x * 256 + threadIdx.x;   // 16*72*64
    const int lane = id & 63;
    const int kc   = (id >> 6) % 72;
    const int ft   = id / (72 * 64);
    const int f  = ft * 16 + (lane & 15);
    const int k0 = kc * 32 + (lane >> 4) * 8;
    unsigned int u[4];
#pragma unroll
    for (int jj = 0; jj < 4; ++jj) {
        float a = w_conv[(size_t)(k0 + 2 * jj) * FF + f];
        float b = w_conv[(size_t)(k0 + 2 * jj + 1) * FF + f];
        u[jj] = pk2_bf16(a, b);
    }
    uint4 v; v.x = u[0]; v.y = u[1]; v.z = u[2]; v.w = u[3];
    *(uint4*)(w_frag + (size_t)id * 8) = v;
}

// ---------------------------------------------------------------------------
// w_off [2304 k][27 o] fp32 -> bf16 B-fragments, o padded to 32 (2 n-tiles)
__global__ __launch_bounds__(256) void k_wofrag(const float* __restrict__ w_off,
                                                unsigned short* __restrict__ wof) {
    const int id = blockIdx.x * 256 + threadIdx.x;   // 2*72*64 = 9216
    const int lane = id & 63;
    const int kc   = (id >> 6) % 72;
    const int nt   = id / (72 * 64);
    const int o  = nt * 16 + (lane & 15);
    const int k0 = kc * 32 + (lane >> 4) * 8;
    unsigned int u[4];
#pragma unroll
    for (int jj = 0; jj < 4; ++jj) {
        float a = (o < 27) ? w_off[(size_t)(k0 + 2 * jj) * 27 + o] : 0.f;
        float b = (o < 27) ? w_off[(size_t)(k0 + 2 * jj + 1) * 27 + o] : 0.f;
        u[jj] = pk2_bf16(a, b);
    }
    uint4 v; v.x = u[0]; v.y = u[1]; v.z = u[2]; v.w = u[3];
    *(uint4*)(wof + (size_t)id * 8) = v;
}

// ---------------------------------------------------------------------------
// Fused: per 32-px block -- (1) offset/mask conv via MFMA -> OM in LDS;
// (2) bilinear gather -> bf16 LDS (double-buffered, 1 barrier/tap) -> MFMA GEMM.
__global__ __launch_bounds__(256) void k_fused(const unsigned short* __restrict__ xb,
                                               const unsigned short* __restrict__ w_frag,
                                               const unsigned short* __restrict__ wof,
                                               const float* __restrict__ b_off,
                                               const float* __restrict__ b_conv,
                                               float* __restrict__ out) {
    __shared__ unsigned short S[2][32 * 264];   // 33.8 KB, px stride 264 (pad 8)
    __shared__ float OM[32][28];                // raw offset-conv outputs (o<27)

    const int t    = threadIdx.x;
    const int lane = t & 63;
    const int wv   = t >> 6;
    const int tb   = (blockIdx.x & 7) * 144 + (blockIdx.x >> 3);   // XCD-local
    const int pb   = tb * 32;
    const size_t ibase = (size_t)(pb / HW) * HW * CC;
    const int ml = lane & 15, q = lane >> 4;

    // ---------------- phase 1: offset conv GEMM (o padded to 32) ----------------
    {
        const int mt = wv & 1, nt = wv >> 1;    // wave -> (m-tile, n-tile)
        const int px = pb + mt * 16 + ml;
        const int rr = px % HW;
        const int py = rr / WW;
        const int pxx = rr - py * WW;
        floatx4 acc = {0.f, 0.f, 0.f, 0.f};
        const short8* W = (const short8*)wof;
        for (int tap = 0; tap < NTAP; ++tap) {
            const int sy = py + tap / 3 - 1;
            const int sx = pxx + tap % 3 - 1;
            const bool valid = (sy >= 0) && (sy < HH) && (sx >= 0) && (sx < WW);
            const unsigned short* rowp = xb + ibase + (size_t)(sy * WW + sx) * CC + q * 8;
#pragma unroll
            for (int c8 = 0; c8 < 8; ++c8) {
                short8 a = valid ? *(const short8*)(rowp + c8 * 32) : zero8();
                acc = __builtin_amdgcn_mfma_f32_16x16x32_bf16(
                    a, W[(size_t)(nt * 72 + tap * 8 + c8) * 64 + lane], acc, 0, 0, 0);
            }
        }
        const int o = nt * 16 + ml;             // C-layout: px = mt*16+q*4+r
        if (o < 27) {
            const float bo = b_off[o];
#pragma unroll
            for (int r = 0; r < 4; ++r)
                OM[mt * 16 + q * 4 + r][o] = acc[r] + bo;
        }
    }
    __syncthreads();

    // ---------------- phase 2: bilinear + main GEMM, double-buffered ----------------
    const int spx = t >> 3;                     // staging pixel (0..31)
    const int c8  = t & 7;                      // staging 8-ch sub-block
    const int rr2 = (pb + spx) % HW;
    const int spy = rr2 / WW;
    const int spxx = rr2 - spy * WW;
    const int f0 = wv * 64;

    floatx4 acc[4][2];
#pragma unroll
    for (int i = 0; i < 4; ++i) { acc[i][0] = floatx4{0.f,0.f,0.f,0.f}; acc[i][1] = floatx4{0.f,0.f,0.f,0.f}; }

    const short8* Wf = (const short8*)w_frag;

    uint4 GA[4], GB[4], GC[4], GD[4];
    float F00, F01, F10, F11;

    auto meta_issue = [&](int tap) {
        const float dy  = OM[spx][tap];
        const float dxv = OM[spx][tap + 9];
        const float mr  = OM[spx][tap + 18];
        const float m = 1.f / (1.f + expf(-mr));
        const float yy = (float)(spy + tap / 3 - 1) + dy;
        const float xx = (float)(spxx + tap % 3 - 1) + dxv;
        const float y0f = floorf(yy), x0f = floorf(xx);
        const int y0 = (int)y0f, x0 = (int)x0f;
        const float wy1 = yy - y0f, wx1 = xx - x0f;
        const float wy0 = 1.f - wy1, wx0 = 1.f - wx1;
        const bool vy0 = (y0 >= 0) && (y0 < HH);
        const bool vy1 = (y0 + 1 >= 0) && (y0 + 1 < HH);
        const bool vx0 = (x0 >= 0) && (x0 < WW);
        const bool vx1 = (x0 + 1 >= 0) && (x0 + 1 < WW);
        const int y0c = min(max(y0, 0), HH - 1);
        const int y1c = min(max(y0 + 1, 0), HH - 1);
        const int x0c = min(max(x0, 0), WW - 1);
        const int x1c = min(max(x0 + 1, 0), WW - 1);
        F00 = (vy0 && vx0) ? wy0 * wx0 * m : 0.f;
        F01 = (vy0 && vx1) ? wy0 * wx1 * m : 0.f;
        F10 = (vy1 && vx0) ? wy1 * wx0 * m : 0.f;
        F11 = (vy1 && vx1) ? wy1 * wx1 * m : 0.f;
        const unsigned short* p00 = xb + ibase + (size_t)(y0c * WW + x0c) * CC + c8 * 8;
        const unsigned short* p01 = xb + ibase + (size_t)(y0c * WW + x1c) * CC + c8 * 8;
        const unsigned short* p10 = xb + ibase + (size_t)(y1c * WW + x0c) * CC + c8 * 8;
        const unsigned short* p11 = xb + ibase + (size_t)(y1c * WW + x1c) * CC + c8 * 8;
#pragma unroll
        for (int j = 0; j < 4; ++j) {
            GA[j] = *(const uint4*)(p00 + j * 64);
            GB[j] = *(const uint4*)(p01 + j * 64);
            GC[j] = *(const uint4*)(p10 + j * 64);
            GD[j] = *(const uint4*)(p11 + j * 64);
        }
    };

    auto blend_store = [&](int buf) {
        unsigned short* Srow = &S[buf][spx * 264 + c8 * 8];
#pragma unroll
        for (int j = 0; j < 4; ++j) {
            uint4 R;
            R.x = pk2_bf16(blo(GA[j].x)*F00 + blo(GB[j].x)*F01 + blo(GC[j].x)*F10 + blo(GD[j].x)*F11,
                           bhi(GA[j].x)*F00 + bhi(GB[j].x)*F01 + bhi(GC[j].x)*F10 + bhi(GD[j].x)*F11);
            R.y = pk2_bf16(blo(GA[j].y)*F00 + blo(GB[j].y)*F01 + blo(GC[j].y)*F10 + blo(GD[j].y)*F11,
                           bhi(GA[j].y)*F00 + bhi(GB[j].y)*F01 + bhi(GC[j].y)*F10 + bhi(GD[j].y)*F11);
            R.z = pk2_bf16(blo(GA[j].z)*F00 + blo(GB[j].z)*F01 + blo(GC[j].z)*F10 + blo(GD[j].z)*F11,
                           bhi(GA[j].z)*F00 + bhi(GB[j].z)*F01 + bhi(GC[j].z)*F10 + bhi(GD[j].z)*F11);
            R.w = pk2_bf16(blo(GA[j].w)*F00 + blo(GB[j].w)*F01 + blo(GC[j].w)*F10 + blo(GD[j].w)*F11,
                           bhi(GA[j].w)*F00 + bhi(GB[j].w)*F01 + bhi(GC[j].w)*F10 + bhi(GD[j].w)*F11);
            *(uint4*)(Srow + j * 64) = R;
        }
    };

    meta_issue(0);
    blend_store(0);
    __syncthreads();

    for (int tap = 0; tap < NTAP; ++tap) {
        const int cur = tap & 1;
        if (tap + 1 < NTAP) meta_issue(tap + 1);    // loads in flight over MFMA
#pragma unroll
        for (int kc = 0; kc < 8; ++kc) {
            short8 a0 = *(const short8*)&S[cur][ml * 264 + kc * 32 + q * 8];
            short8 a1 = *(const short8*)&S[cur][(16 + ml) * 264 + kc * 32 + q * 8];
#pragma unroll
            for (int nt = 0; nt < 4; ++nt) {
                short8 bfr = Wf[(size_t)((wv * 4 + nt) * 72 + tap * 8 + kc) * 64 + lane];
                acc[nt][0] = __builtin_amdgcn_mfma_f32_16x16x32_bf16(a0, bfr, acc[nt][0], 0, 0, 0);
                acc[nt][1] = __builtin_amdgcn_mfma_f32_16x16x32_bf16(a1, bfr, acc[nt][1], 0, 0, 0);
            }
        }
        if (tap + 1 < NTAP) blend_store(cur ^ 1);
        __syncthreads();
    }

    // epilogue: col = lane&15 (f), row = (lane>>4)*4+reg (px)
#pragma unroll
    for (int nt = 0; nt < 4; ++nt) {
        const int f = f0 + nt * 16 + ml;
        const float bc = b_conv[f];
#pragma unroll
        for (int mt = 0; mt < 2; ++mt) {
#pragma unroll
            for (int r = 0; r < 4; ++r) {
                const int px = pb + mt * 16 + q * 4 + r;
                out[(size_t)px * FF + f] = acc[nt][mt][r] + bc;
            }
        }
    }
}

// ---------------------------------------------------------------------------
extern "C" void kernel_launch(void* const* d_in, const int* in_sizes, int n_in,
                              void* d_out, int out_size, void* d_ws, size_t ws_size,
                              hipStream_t stream) {
    const float* x      = (const float*)d_in[0];
    const float* w_off  = (const float*)d_in[1];
    const float* b_off  = (const float*)d_in[2];
    const float* w_conv = (const float*)d_in[3];
    const float* b_conv = (const float*)d_in[4];
    float* out = (float*)d_out;
    float* ws  = (float*)d_ws;

    unsigned short* w_frag = (unsigned short*)(ws + WF_OFF);
    unsigned short* wof    = (unsigned short*)(ws + WOF_OFF);
    unsigned short* xb     = (unsigned short*)(ws + XB_OFF);

    hipLaunchKernelGGL(k_cast, dim3(PTOT * CC / (256 * 8)), dim3(256), 0, stream, x, xb);
    hipLaunchKernelGGL(k_wfrag, dim3((16 * 72 * 64) / 256), dim3(256), 0, stream, w_conv, w_frag);
    hipLaunchKernelGGL(k_wofrag, dim3((2 * 72 * 64) / 256), dim3(256), 0, stream, w_off, wof);
    hipLaunchKernelGGL(k_fused, dim3(PTOT / 32), dim3(256), 0, stream,
                       xb, w_frag, wof, b_off, b_conv, out);
}

// Round 5
// 299.430 us; speedup vs baseline: 1.0739x; 1.0739x over previous
//
#include <hip/hip_runtime.h>
#include <math.h>

#define BB 4
#define HH 96
#define WW 96
#define CC 256
#define FF 256
#define HW (HH*WW)          // 9216
#define PTOT (BB*HW)        // 36864
#define NTAP 9

// workspace layout (float units):
//   w_frag: [16][72][64][8] bf16 (main conv B-frags)   294912
//   wof   : [2][72][64][8] bf16 (offset conv B-frags)   36864
//   xb16  : [PTOT][256] bf16                           4718592
#define WF_OFF  0
#define WOF_OFF (WF_OFF + 16*72*64*8/2)
#define XB_OFF  (WOF_OFF + 2*72*64*8/2)

typedef __attribute__((ext_vector_type(8))) short short8;   // 8 bf16
typedef __attribute__((ext_vector_type(4))) float floatx4;  // MFMA acc

struct alignas(16) F4 { float x, y, z, w; };
__device__ __forceinline__ F4 ldf4(const float* p) { return *(const F4*)p; }

__device__ __forceinline__ unsigned int pk2_bf16(float a, float b) {
    unsigned int ua = __float_as_uint(a); ua += 0x7FFFu + ((ua >> 16) & 1u);
    unsigned int ub = __float_as_uint(b); ub += 0x7FFFu + ((ub >> 16) & 1u);
    return (ua >> 16) | (ub & 0xFFFF0000u);
}
__device__ __forceinline__ float blo(unsigned int u) { return __uint_as_float(u << 16); }
__device__ __forceinline__ float bhi(unsigned int u) { return __uint_as_float(u & 0xFFFF0000u); }
__device__ __forceinline__ short8 zero8() { short8 v = {0,0,0,0,0,0,0,0}; return v; }

// Workgroup barrier WITHOUT the vmcnt(0) drain of __syncthreads():
// LDS producer/consumer only needs lgkmcnt(0). Global loads (gathers,
// B-frag prefetch) stay in flight across the barrier — the backend inserts
// precise vmcnt(N) waits at their use points. "memory" clobber pins ordering.
__device__ __forceinline__ void lgkm_barrier() {
    __asm__ volatile("s_waitcnt lgkmcnt(0)\n\ts_barrier" ::: "memory");
}

// ---------------------------------------------------------------------------
// One prep kernel (3 launch slots -> 1):
//   blocks [0,4608):    x fp32 -> bf16 (8 elems/thread)
//   blocks [4608,4896): w_conv -> bf16 B-fragments (MFMA load order)
//   blocks [4896,4932): w_off  -> bf16 B-fragments (o padded to 32)
__global__ __launch_bounds__(256) void k_prep(const float* __restrict__ x,
                                              const float* __restrict__ w_conv,
                                              const float* __restrict__ w_off,
                                              unsigned short* __restrict__ xb,
                                              unsigned short* __restrict__ w_frag,
                                              unsigned short* __restrict__ wof) {
    const int bid = blockIdx.x, t = threadIdx.x;
    if (bid < 4608) {
        const int id = bid * 256 + t;
        const F4 a = ldf4(x + (size_t)id * 8);
        const F4 b = ldf4(x + (size_t)id * 8 + 4);
        uint4 v;
        v.x = pk2_bf16(a.x, a.y); v.y = pk2_bf16(a.z, a.w);
        v.z = pk2_bf16(b.x, b.y); v.w = pk2_bf16(b.z, b.w);
        *(uint4*)(xb + (size_t)id * 8) = v;
    } else if (bid < 4896) {
        const int id = (bid - 4608) * 256 + t;      // 16*72*64
        const int lane = id & 63;
        const int kc   = (id >> 6) % 72;
        const int ft   = id / (72 * 64);
        const int f  = ft * 16 + (lane & 15);
        const int k0 = kc * 32 + (lane >> 4) * 8;
        unsigned int u[4];
#pragma unroll
        for (int jj = 0; jj < 4; ++jj) {
            float a = w_conv[(size_t)(k0 + 2 * jj) * FF + f];
            float b = w_conv[(size_t)(k0 + 2 * jj + 1) * FF + f];
            u[jj] = pk2_bf16(a, b);
        }
        uint4 v; v.x = u[0]; v.y = u[1]; v.z = u[2]; v.w = u[3];
        *(uint4*)(w_frag + (size_t)id * 8) = v;
    } else {
        const int id = (bid - 4896) * 256 + t;      // 2*72*64
        const int lane = id & 63;
        const int kc   = (id >> 6) % 72;
        const int nt   = id / (72 * 64);
        const int o  = nt * 16 + (lane & 15);
        const int k0 = kc * 32 + (lane >> 4) * 8;
        unsigned int u[4];
#pragma unroll
        for (int jj = 0; jj < 4; ++jj) {
            float a = (o < 27) ? w_off[(size_t)(k0 + 2 * jj) * 27 + o] : 0.f;
            float b = (o < 27) ? w_off[(size_t)(k0 + 2 * jj + 1) * 27 + o] : 0.f;
            u[jj] = pk2_bf16(a, b);
        }
        uint4 v; v.x = u[0]; v.y = u[1]; v.z = u[2]; v.w = u[3];
        *(uint4*)(wof + (size_t)id * 8) = v;
    }
}

// ---------------------------------------------------------------------------
// Fused DCN: phase 1 offset/mask conv (MFMA) -> OM in LDS;
// phase 2 bilinear gather -> bf16 LDS (single buffer) -> MFMA GEMM.
// Barriers never drain vmcnt; gathers/B-loads stay in flight across taps.
__global__ __launch_bounds__(256) void k_fused(const unsigned short* __restrict__ xb,
                                               const unsigned short* __restrict__ w_frag,
                                               const unsigned short* __restrict__ wof,
                                               const float* __restrict__ b_off,
                                               const float* __restrict__ b_conv,
                                               float* __restrict__ out) {
    __shared__ unsigned short S[32 * 264];      // 16.9 KB, px stride 264 (pad 8)
    __shared__ float OM[32][28];                // offset-conv raw outputs (o<27)

    const int t    = threadIdx.x;
    const int lane = t & 63;
    const int wv   = t >> 6;
    const int tb   = (blockIdx.x & 7) * 144 + (blockIdx.x >> 3);   // XCD-local
    const int pb   = tb * 32;
    const size_t ibase = (size_t)(pb / HW) * HW * CC;
    const int ml = lane & 15, q = lane >> 4;

    // ---------------- phase 1: offset conv GEMM (o padded to 32) ----------------
    {
        const int mt = wv & 1, nt = wv >> 1;    // wave -> (m-tile, n-tile)
        const int px = pb + mt * 16 + ml;
        const int rr = px % HW;
        const int py = rr / WW;
        const int pxx = rr - py * WW;
        floatx4 acc = {0.f, 0.f, 0.f, 0.f};
        const short8* W = (const short8*)wof;
        for (int tap = 0; tap < NTAP; ++tap) {
            const int sy = py + tap / 3 - 1;
            const int sx = pxx + tap % 3 - 1;
            const bool valid = (sy >= 0) && (sy < HH) && (sx >= 0) && (sx < WW);
            const unsigned short* rowp = xb + ibase + (size_t)(sy * WW + sx) * CC + q * 8;
#pragma unroll
            for (int c8 = 0; c8 < 8; ++c8) {
                short8 a = valid ? *(const short8*)(rowp + c8 * 32) : zero8();
                acc = __builtin_amdgcn_mfma_f32_16x16x32_bf16(
                    a, W[(size_t)(nt * 72 + tap * 8 + c8) * 64 + lane], acc, 0, 0, 0);
            }
        }
        const int o = nt * 16 + ml;             // C-layout: px = mt*16+q*4+r
        if (o < 27) {
            const float bo = b_off[o];
#pragma unroll
            for (int r = 0; r < 4; ++r)
                OM[mt * 16 + q * 4 + r][o] = acc[r] + bo;
        }
    }
    __syncthreads();    // once per block; full drain acceptable here

    // ---------------- phase 2 ----------------
    const int spx = t >> 3;                     // staging pixel (0..31)
    const int c8  = t & 7;                      // staging 8-ch sub-block
    const int rr2 = (pb + spx) % HW;
    const int spy = rr2 / WW;
    const int spxx = rr2 - spy * WW;
    const int f0 = wv * 64;

    floatx4 acc[4][2];
#pragma unroll
    for (int i = 0; i < 4; ++i) { acc[i][0] = floatx4{0.f,0.f,0.f,0.f}; acc[i][1] = floatx4{0.f,0.f,0.f,0.f}; }

    const short8* Wl = (const short8*)w_frag + lane;

    uint4 GA[4], GB[4], GC[4], GD[4];
    float F00, F01, F10, F11;

    auto meta_issue = [&](int tap) {
        const float dy  = OM[spx][tap];
        const float dxv = OM[spx][tap + 9];
        const float mr  = OM[spx][tap + 18];
        const float m = 1.f / (1.f + __expf(-mr));
        const float yy = (float)(spy + tap / 3 - 1) + dy;
        const float xx = (float)(spxx + tap % 3 - 1) + dxv;
        const float y0f = floorf(yy), x0f = floorf(xx);
        const int y0 = (int)y0f, x0 = (int)x0f;
        const float wy1 = yy - y0f, wx1 = xx - x0f;
        const float wy0 = 1.f - wy1, wx0 = 1.f - wx1;
        const bool vy0 = (y0 >= 0) && (y0 < HH);
        const bool vy1 = (y0 + 1 >= 0) && (y0 + 1 < HH);
        const bool vx0 = (x0 >= 0) && (x0 < WW);
        const bool vx1 = (x0 + 1 >= 0) && (x0 + 1 < WW);
        const int y0c = min(max(y0, 0), HH - 1);
        const int y1c = min(max(y0 + 1, 0), HH - 1);
        const int x0c = min(max(x0, 0), WW - 1);
        const int x1c = min(max(x0 + 1, 0), WW - 1);
        F00 = (vy0 && vx0) ? wy0 * wx0 * m : 0.f;
        F01 = (vy0 && vx1) ? wy0 * wx1 * m : 0.f;
        F10 = (vy1 && vx0) ? wy1 * wx0 * m : 0.f;
        F11 = (vy1 && vx1) ? wy1 * wx1 * m : 0.f;
        const unsigned short* p00 = xb + ibase + (size_t)(y0c * WW + x0c) * CC + c8 * 8;
        const unsigned short* p01 = xb + ibase + (size_t)(y0c * WW + x1c) * CC + c8 * 8;
        const unsigned short* p10 = xb + ibase + (size_t)(y1c * WW + x0c) * CC + c8 * 8;
        const unsigned short* p11 = xb + ibase + (size_t)(y1c * WW + x1c) * CC + c8 * 8;
#pragma unroll
        for (int j = 0; j < 4; ++j) {
            GA[j] = *(const uint4*)(p00 + j * 64);
            GB[j] = *(const uint4*)(p01 + j * 64);
            GC[j] = *(const uint4*)(p10 + j * 64);
            GD[j] = *(const uint4*)(p11 + j * 64);
        }
    };

    auto blend_store = [&]() {
        unsigned short* Srow = &S[spx * 264 + c8 * 8];
#pragma unroll
        for (int j = 0; j < 4; ++j) {
            uint4 R;
            R.x = pk2_bf16(blo(GA[j].x)*F00 + blo(GB[j].x)*F01 + blo(GC[j].x)*F10 + blo(GD[j].x)*F11,
                           bhi(GA[j].x)*F00 + bhi(GB[j].x)*F01 + bhi(GC[j].x)*F10 + bhi(GD[j].x)*F11);
            R.y = pk2_bf16(blo(GA[j].y)*F00 + blo(GB[j].y)*F01 + blo(GC[j].y)*F10 + blo(GD[j].y)*F11,
                           bhi(GA[j].y)*F00 + bhi(GB[j].y)*F01 + bhi(GC[j].y)*F10 + bhi(GD[j].y)*F11);
            R.z = pk2_bf16(blo(GA[j].z)*F00 + blo(GB[j].z)*F01 + blo(GC[j].z)*F10 + blo(GD[j].z)*F11,
                           bhi(GA[j].z)*F00 + bhi(GB[j].z)*F01 + bhi(GC[j].z)*F10 + bhi(GD[j].z)*F11);
            R.w = pk2_bf16(blo(GA[j].w)*F00 + blo(GB[j].w)*F01 + blo(GC[j].w)*F10 + blo(GD[j].w)*F11,
                           bhi(GA[j].w)*F00 + bhi(GB[j].w)*F01 + bhi(GC[j].w)*F10 + bhi(GD[j].w)*F11);
            *(uint4*)(Srow + j * 64) = R;
        }
    };

    meta_issue(0);    // tap-0 gathers in flight

    for (int tap = 0; tap < NTAP; ++tap) {
        blend_store();                      // vmcnt(N) waits only on this tap's gathers
        lgkm_barrier();                     // S visible; gathers/B stay in flight
        if (tap + 1 < NTAP) meta_issue(tap + 1);   // next gathers fly over MFMAs

        // MFMA over S with explicit next-kc B prefetch
        const size_t wb = ((size_t)(wv * 4) * 72 + tap * 8) * 64;
        short8 bcur[4], bnext[4];
#pragma unroll
        for (int nt = 0; nt < 4; ++nt) bcur[nt] = Wl[wb + (size_t)(nt * 72) * 64];
#pragma unroll
        for (int kc = 0; kc < 8; ++kc) {
            short8 a0 = *(const short8*)&S[ml * 264 + kc * 32 + q * 8];
            short8 a1 = *(const short8*)&S[(16 + ml) * 264 + kc * 32 + q * 8];
            if (kc < 7) {
#pragma unroll
                for (int nt = 0; nt < 4; ++nt)
                    bnext[nt] = Wl[wb + (size_t)(nt * 72 + kc + 1) * 64];
            }
#pragma unroll
            for (int nt = 0; nt < 4; ++nt) {
                acc[nt][0] = __builtin_amdgcn_mfma_f32_16x16x32_bf16(a0, bcur[nt], acc[nt][0], 0, 0, 0);
                acc[nt][1] = __builtin_amdgcn_mfma_f32_16x16x32_bf16(a1, bcur[nt], acc[nt][1], 0, 0, 0);
            }
#pragma unroll
            for (int nt = 0; nt < 4; ++nt) bcur[nt] = bnext[nt];
        }
        if (tap + 1 < NTAP) lgkm_barrier(); // all waves done reading S before overwrite
    }

    // epilogue: col = lane&15 (f), row = (lane>>4)*4+reg (px)
#pragma unroll
    for (int nt = 0; nt < 4; ++nt) {
        const int f = f0 + nt * 16 + ml;
        const float bc = b_conv[f];
#pragma unroll
        for (int mt = 0; mt < 2; ++mt) {
#pragma unroll
            for (int r = 0; r < 4; ++r) {
                const int px = pb + mt * 16 + q * 4 + r;
                out[(size_t)px * FF + f] = acc[nt][mt][r] + bc;
            }
        }
    }
}

// ---------------------------------------------------------------------------
extern "C" void kernel_launch(void* const* d_in, const int* in_sizes, int n_in,
                              void* d_out, int out_size, void* d_ws, size_t ws_size,
                              hipStream_t stream) {
    const float* x      = (const float*)d_in[0];
    const float* w_off  = (const float*)d_in[1];
    const float* b_off  = (const float*)d_in[2];
    const float* w_conv = (const float*)d_in[3];
    const float* b_conv = (const float*)d_in[4];
    float* out = (float*)d_out;
    float* ws  = (float*)d_ws;

    unsigned short* w_frag = (unsigned short*)(ws + WF_OFF);
    unsigned short* wof    = (unsigned short*)(ws + WOF_OFF);
    unsigned short* xb     = (unsigned short*)(ws + XB_OFF);

    hipLaunchKernelGGL(k_prep, dim3(4932), dim3(256), 0, stream,
                       x, w_conv, w_off, xb, w_frag, wof);
    hipLaunchKernelGGL(k_fused, dim3(PTOT / 32), dim3(256), 0, stream,
                       xb, w_frag, wof, b_off, b_conv, out);
}